// Round 9
// baseline (201.283 us; speedup 1.0000x reference)
//
#include <hip/hip_runtime.h>
#include <math.h>

#define CB 16          // class_bit
#define ALPHA 0.1f
#define LOG2E 1.4426950408889634f
#define LN2F  0.6931471805599453f
#define NT 4           // t-tiles per block (software pipeline depth)

typedef __bf16 bf16x8 __attribute__((ext_vector_type(8)));
typedef float  f32x16 __attribute__((ext_vector_type(16)));

__device__ inline float block_reduce_256(float v, float* red) {
    #pragma unroll
    for (int off = 32; off > 0; off >>= 1) v += __shfl_down(v, off, 64);
    int lane = threadIdx.x & 63;
    int wid  = threadIdx.x >> 6;
    if (lane == 0) red[wid] = v;
    __syncthreads();
    float s = 0.f;
    if (threadIdx.x == 0) {
        int nw = blockDim.x >> 6;
        for (int w = 0; w < nw; ++w) s += red[w];
    }
    return s;
}

// Fused prep (unchanged from Round 8):
//  blocks [0, nub):        u_ = einsum + u_f32 / u_bf(scaled log2e) / quant partials
//  blocks [nub, nub+n_cls): vvec/wvec from u,y,w_D directly
__global__ __launch_bounds__(256) void prep_kernel(
        const float* __restrict__ u, const float* __restrict__ y,
        const float* __restrict__ w_D,
        float* __restrict__ u_f32, __bf16* __restrict__ u_bf,
        float* __restrict__ quant_partials,
        float* __restrict__ vvec, float* __restrict__ wvec,
        int n_bs, int bit, int n_cls, int nub) {
    __shared__ float red[4];
    __shared__ float yus[4][64];
    __shared__ float sus[4][64];
    if ((int)blockIdx.x < nub) {
        int idx = blockIdx.x * 256 + threadIdx.x;
        int total = n_bs * n_cls * CB;
        float q = 0.f;
        if (idx < total) {
            int d = idx & (CB - 1);
            int c = (idx / CB) % n_cls;
            int b = idx / (CB * n_cls);
            const float* __restrict__ ur = u + (size_t)b * bit;
            const float* __restrict__ w  = w_D + (size_t)c * bit * CB + d;
            float s = 0.f;
            for (int k = 0; k < bit; ++k) s = fmaf(ur[k], w[k * CB], s);
            u_f32[idx] = s;
            u_bf[((size_t)c * n_bs + b) * CB + d] = (__bf16)(s * LOG2E);
            float sgn = (s > 0.f) ? 1.f : ((s < 0.f) ? -1.f : 0.f);
            float dd = s - sgn;
            q = dd * dd;
        }
        float bs = block_reduce_256(q, red);
        if (threadIdx.x == 0) quant_partials[blockIdx.x] = bs;
    } else {
        const int c  = blockIdx.x - nub;
        const int kk = threadIdx.x & 63;       // k index (bit <= 64)
        const int sl = threadIdx.x >> 6;       // 4 b-slices
        float yv = 0.f, sv = 0.f;
        if (kk < bit) {
            const int bpp = n_bs >> 2;
            for (int b = sl * bpp; b < (sl + 1) * bpp; ++b) {
                float uv = u[(size_t)b * bit + kk];
                sv += uv;
                yv = fmaf(y[(size_t)b * n_cls + c], uv, yv);
            }
        }
        yus[sl][kk] = yv; sus[sl][kk] = sv;
        __syncthreads();
        if (sl == 0 && kk < bit) {
            yus[0][kk] = yus[0][kk] + yus[1][kk] + yus[2][kk] + yus[3][kk];
            sus[0][kk] = sus[0][kk] + sus[1][kk] + sus[2][kk] + sus[3][kk];
        }
        __syncthreads();
        if (threadIdx.x < CB) {
            const int d = threadIdx.x;
            const float* __restrict__ wdc = w_D + (size_t)c * bit * CB + d;
            float v = 0.f, w = 0.f;
            for (int k = 0; k < bit; ++k) {
                float wv = wdc[k * CB];
                v = fmaf(yus[0][k], wv, v);
                w = fmaf(sus[0][k], wv, w);
            }
            vvec[(size_t)c * CB + d] = v;
            wvec[(size_t)c * CB + d] = w;
        }
    }
}

// One block = NT consecutive 32-row t-tiles x 4 classes (one class per wave).
// B-frags / vvec / wvec / ind-scan / reduction amortized over NT tiles.
// A-rows + Yv of tile i+1 prefetched before epilogue of tile i (latency hiding).
// No fences, no cross-block sync (Round 6/7 lesson).
__global__ __launch_bounds__(256, 4) void loss_main_mfma(
        const float* __restrict__ y, const float* __restrict__ U,
        const float* __restrict__ Yb, const float* __restrict__ u_f32,
        const __bf16* __restrict__ u_bf,
        const float* __restrict__ vvec, const float* __restrict__ wvec,
        const int* __restrict__ ind, float* __restrict__ partials,
        int n_bs, int n_cls, int n_train) {
    __shared__ float red[4];
    __shared__ int pflag[NT * 32];
    const int tid  = threadIdx.x;
    const int lane = tid & 63;
    const int wid  = tid >> 6;
    const int c    = blockIdx.x * 4 + wid;
    const int bt0  = blockIdx.y * (NT * 32);
    const int r    = lane & 31;
    const int h    = lane >> 5;

    for (int i = tid; i < NT * 32; i += 256) pflag[i] = -1;
    __syncthreads();
    if (tid < n_bs) {
        unsigned rl = (unsigned)(ind[tid] - bt0);
        if (rl < (unsigned)(NT * 32)) pflag[rl] = tid;   // rows distinct
    }

    // B fragments: once per block (same class for all NT tiles)
    const __bf16* __restrict__ ub = u_bf + (size_t)c * n_bs * CB;
    bf16x8 B[4];
    #pragma unroll
    for (int bt = 0; bt < 4; ++bt)
        B[bt] = *(const bf16x8*)(ub + (size_t)(bt * 32 + r) * CB + h * 8);

    // vvec/wvec in registers: once per block
    const float* __restrict__ vp = vvec + (size_t)c * CB + h * 8;
    const float* __restrict__ wp = wvec + (size_t)c * CB + h * 8;
    float4 vp0 = *(const float4*)(vp);
    float4 vp1 = *(const float4*)(vp + 4);
    float4 wp0 = *(const float4*)(wp);
    float4 wp1 = *(const float4*)(wp + 4);

    __syncthreads();                        // pflag complete

    // prefetch tile 0
    int rowp = bt0 + r;
    int rcp  = (rowp < n_train) ? rowp : (n_train - 1);
    const float* __restrict__ arp = U + ((size_t)rcp * n_cls + c) * CB + h * 8;
    float4 a0c = *(const float4*)(arp);
    float4 a1c = *(const float4*)(arp + 4);
    float  Yvc = Yb[(size_t)rcp * n_cls + c];

    float accA = 0.f;        // sum |ip'|
    float accL = 0.f;        // sum log2(prod-per-tile)
    float linC = 0.f;        // 0.5*sideW - sideS accumulated
    f32x16 zc = {};

    #pragma unroll
    for (int it = 0; it < NT; ++it) {
        // issue next tile's loads before this tile's compute
        float4 a0n, a1n; float Yvn = 0.f;
        if (it + 1 < NT) {
            int rown = bt0 + (it + 1) * 32 + r;
            int rcn  = (rown < n_train) ? rown : (n_train - 1);
            const float* __restrict__ arn =
                U + ((size_t)rcn * n_cls + c) * CB + h * 8;
            a0n = *(const float4*)(arn);
            a1n = *(const float4*)(arn + 4);
            Yvn = Yb[(size_t)rcn * n_cls + c];
        }

        // patch current tile (rare)
        const int pf = pflag[it * 32 + r];
        if (pf >= 0) {
            const float* __restrict__ src =
                u_f32 + ((size_t)pf * n_cls + c) * CB + h * 8;
            a0c = *(const float4*)(src);
            a1c = *(const float4*)(src + 4);
            Yvc = y[(size_t)pf * n_cls + c];
        }
        const int rowc = bt0 + it * 32 + r;
        if (rowc >= n_train) {
            a0c = make_float4(0.f, 0.f, 0.f, 0.f); a1c = a0c; Yvc = 0.f;
        }

        // side dots
        float sv = a0c.x*vp0.x + a0c.y*vp0.y + a0c.z*vp0.z + a0c.w*vp0.w
                 + a1c.x*vp1.x + a1c.y*vp1.y + a1c.z*vp1.z + a1c.w*vp1.w;
        float sw = a0c.x*wp0.x + a0c.y*wp0.y + a0c.z*wp0.z + a0c.w*wp0.w
                 + a1c.x*wp1.x + a1c.y*wp1.y + a1c.z*wp1.z + a1c.w*wp1.w;
        linC += 0.5f * sw - Yvc * sv;

        bf16x8 A;
        A[0] = (__bf16)a0c.x; A[1] = (__bf16)a0c.y;
        A[2] = (__bf16)a0c.z; A[3] = (__bf16)a0c.w;
        A[4] = (__bf16)a1c.x; A[5] = (__bf16)a1c.y;
        A[6] = (__bf16)a1c.z; A[7] = (__bf16)a1c.w;

        float pp = 1.f;      // per-tile product: 64 factors in (1,2] -> <= 2^64
        #pragma unroll
        for (int bt = 0; bt < 4; ++bt) {
            f32x16 D = __builtin_amdgcn_mfma_f32_32x32x16_bf16(A, B[bt], zc,
                                                               0, 0, 0);
            float a[16];
            #pragma unroll
            for (int j = 0; j < 16; ++j) {
                float ipa = fabsf(D[j]);
                a[j] = 1.0f + __builtin_amdgcn_exp2f(-ipa);  // src modifiers
                accA += ipa;
            }
            #pragma unroll
            for (int s = 1; s < 16; s <<= 1)
                #pragma unroll
                for (int j = 0; j < 16; j += 2 * s) a[j] *= a[j + s];
            pp *= a[0];
        }
        accL += __builtin_amdgcn_logf(pp);   // v_log_f32 = log2

        a0c = a0n; a1c = a1n; Yvc = Yvn;     // rotate pipeline
    }

    // combined per-lane contribution; pad rows contribute exactly LN2F each
    float contrib = LN2F * accL + (0.5f * LN2F) * accA + linC;

    #pragma unroll
    for (int off = 32; off > 0; off >>= 1)
        contrib += __shfl_down(contrib, off, 64);
    if (lane == 0) red[wid] = contrib;
    __syncthreads();
    if (tid == 0) {
        int bid = blockIdx.y * gridDim.x + blockIdx.x;
        partials[bid] = red[0] + red[1] + red[2] + red[3];
    }
}

__global__ __launch_bounds__(256) void finalize_kernel(
        const float* __restrict__ partials, int nblk,
        const float* __restrict__ quant_partials, int n_quant,
        float* __restrict__ out, double pad_corr,
        double like_scale, double quant_scale) {
    double s = 0.0, q = 0.0;
    for (int i = threadIdx.x; i < nblk; i += 256) s += (double)partials[i];
    for (int i = threadIdx.x; i < n_quant; i += 256) q += (double)quant_partials[i];
    #pragma unroll
    for (int off = 32; off > 0; off >>= 1) {
        s += __shfl_down(s, off, 64);
        q += __shfl_down(q, off, 64);
    }
    __shared__ double dred[4][2];
    int lane = threadIdx.x & 63, wid = threadIdx.x >> 6;
    if (lane == 0) { dred[wid][0] = s; dred[wid][1] = q; }
    __syncthreads();
    if (threadIdx.x == 0) {
        double S = dred[0][0] + dred[1][0] + dred[2][0] + dred[3][0];
        double Q = dred[0][1] + dred[1][1] + dred[2][1] + dred[3][1];
        out[0] = (float)((S - pad_corr) * like_scale + Q * quant_scale);
    }
}

extern "C" void kernel_launch(void* const* d_in, const int* in_sizes, int n_in,
                              void* d_out, int out_size, void* d_ws, size_t ws_size,
                              hipStream_t stream) {
    const float* u   = (const float*)d_in[0];
    const float* y   = (const float*)d_in[1];
    const int*   ind = (const int*)d_in[2];
    const float* U   = (const float*)d_in[3];
    const float* Yb  = (const float*)d_in[4];
    const float* w_D = (const float*)d_in[5];

    const int n_bs    = in_sizes[2];             // 128
    const int bit     = in_sizes[0] / n_bs;      // 48
    const int n_cls   = in_sizes[1] / n_bs;      // 100
    const int n_train = in_sizes[4] / n_cls;     // 10000

    const int totalU = n_bs * n_cls * CB;
    const int nub    = (totalU + 255) / 256;     // 800
    const int ntile  = (n_train + 31) / 32;      // 313
    const int gy     = (ntile + NT - 1) / NT;    // 79
    const int gx     = (n_cls + 3) / 4;          // 25
    const int nblk   = gy * gx;

    char* ws = (char*)d_ws;
    size_t off = 0;
    float* u_f32 = (float*)(ws + off);          off += (size_t)totalU * 4;
    __bf16* u_bf = (__bf16*)(ws + off);         off += (size_t)totalU * 2;
    off = (off + 15) & ~(size_t)15;
    float* vvec = (float*)(ws + off);           off += (size_t)n_cls * CB * 4;
    float* wvec = (float*)(ws + off);           off += (size_t)n_cls * CB * 4;
    float* quant_partials = (float*)(ws + off); off += (size_t)nub * 4;
    off = (off + 15) & ~(size_t)15;
    float* partials = (float*)(ws + off);       off += (size_t)nblk * 4;

    prep_kernel<<<nub + n_cls, 256, 0, stream>>>(
        u, y, w_D, u_f32, u_bf, quant_partials, vvec, wvec,
        n_bs, bit, n_cls, nub);

    loss_main_mfma<<<dim3(gx, gy), 256, 0, stream>>>(
        y, U, Yb, u_f32, u_bf, vvec, wvec, ind, partials,
        n_bs, n_cls, n_train);

    const double ln2 = 0.6931471805599453;
    const double n_pad = (double)((long long)(gy * NT * 32 - n_train) *
                                  (long long)n_bs * (long long)n_cls);
    const double pad_corr    = ln2 * n_pad;
    const double like_scale  = 1.0 / ((double)n_bs * n_train * n_cls);
    const double quant_scale = (double)ALPHA / (double)totalU;

    finalize_kernel<<<1, 256, 0, stream>>>(partials, nblk, quant_partials, nub,
                                           (float*)d_out, pad_corr,
                                           like_scale, quant_scale);
}

// Round 10
// 64.846 us; speedup vs baseline: 3.1040x; 3.1040x over previous
//
#include <hip/hip_runtime.h>
#include <math.h>

#define CB 16          // class_bit
#define ALPHA 0.1f
#define LOG2E 1.4426950408889634f
#define LN2F  0.6931471805599453f

typedef __bf16 bf16x8 __attribute__((ext_vector_type(8)));
typedef float  f32x16 __attribute__((ext_vector_type(16)));
typedef float  f32x2  __attribute__((ext_vector_type(2)));

__device__ inline float block_reduce_256(float v, float* red) {
    #pragma unroll
    for (int off = 32; off > 0; off >>= 1) v += __shfl_down(v, off, 64);
    int lane = threadIdx.x & 63;
    int wid  = threadIdx.x >> 6;
    if (lane == 0) red[wid] = v;
    __syncthreads();
    float s = 0.f;
    if (threadIdx.x == 0) {
        int nw = blockDim.x >> 6;
        for (int w = 0; w < nw; ++w) s += red[w];
    }
    return s;
}

// Fused prep (unchanged from Round 8):
//  blocks [0, nub):        u_ = einsum -> u_f32 / u_bf(scaled log2e) / quant partials
//  blocks [nub, nub+n_cls): vvec/wvec from u,y,w_D directly
__global__ __launch_bounds__(256) void prep_kernel(
        const float* __restrict__ u, const float* __restrict__ y,
        const float* __restrict__ w_D,
        float* __restrict__ u_f32, __bf16* __restrict__ u_bf,
        float* __restrict__ quant_partials,
        float* __restrict__ vvec, float* __restrict__ wvec,
        int n_bs, int bit, int n_cls, int nub) {
    __shared__ float red[4];
    __shared__ float yus[4][64];
    __shared__ float sus[4][64];
    if ((int)blockIdx.x < nub) {
        int idx = blockIdx.x * 256 + threadIdx.x;
        int total = n_bs * n_cls * CB;
        float q = 0.f;
        if (idx < total) {
            int d = idx & (CB - 1);
            int c = (idx / CB) % n_cls;
            int b = idx / (CB * n_cls);
            const float* __restrict__ ur = u + (size_t)b * bit;
            const float* __restrict__ w  = w_D + (size_t)c * bit * CB + d;
            float s = 0.f;
            for (int k = 0; k < bit; ++k) s = fmaf(ur[k], w[k * CB], s);
            u_f32[idx] = s;
            u_bf[((size_t)c * n_bs + b) * CB + d] = (__bf16)(s * LOG2E);
            float sgn = (s > 0.f) ? 1.f : ((s < 0.f) ? -1.f : 0.f);
            float dd = s - sgn;
            q = dd * dd;
        }
        float bs = block_reduce_256(q, red);
        if (threadIdx.x == 0) quant_partials[blockIdx.x] = bs;
    } else {
        const int c  = blockIdx.x - nub;
        const int kk = threadIdx.x & 63;       // k index (bit <= 64)
        const int sl = threadIdx.x >> 6;       // 4 b-slices
        float yv = 0.f, sv = 0.f;
        if (kk < bit) {
            const int bpp = n_bs >> 2;
            for (int b = sl * bpp; b < (sl + 1) * bpp; ++b) {
                float uv = u[(size_t)b * bit + kk];
                sv += uv;
                yv = fmaf(y[(size_t)b * n_cls + c], uv, yv);
            }
        }
        yus[sl][kk] = yv; sus[sl][kk] = sv;
        __syncthreads();
        if (sl == 0 && kk < bit) {
            yus[0][kk] = yus[0][kk] + yus[1][kk] + yus[2][kk] + yus[3][kk];
            sus[0][kk] = sus[0][kk] + sus[1][kk] + sus[2][kk] + sus[3][kk];
        }
        __syncthreads();
        if (threadIdx.x < CB) {
            const int d = threadIdx.x;
            const float* __restrict__ wdc = w_D + (size_t)c * bit * CB + d;
            float v = 0.f, w = 0.f;
            for (int k = 0; k < bit; ++k) {
                float wv = wdc[k * CB];
                v = fmaf(yus[0][k], wv, v);
                w = fmaf(sus[0][k], wv, w);
            }
            vvec[(size_t)c * CB + d] = v;
            wvec[(size_t)c * CB + d] = w;
        }
    }
}

// One block = 32-row t-tile x 4 classes (one class per wave, 4 MFMAs/wave).
// R8 structure (known good). Epilogue rewritten on f32x2 so LLVM can emit
// CDNA packed-f32 VALU ops (v_pk_max/add/mul_f32): |D| = max(d,-d),
// accA/1+e/product-tree all pairwise. exp2 stays scalar (trans pipe).
// No fences, no cross-block sync (Round 6/7 lesson); no deep per-thread
// pipelining (Round 9 lesson: spills to scratch).
__global__ __launch_bounds__(256, 4) void loss_main_mfma(
        const float* __restrict__ y, const float* __restrict__ U,
        const float* __restrict__ Yb, const float* __restrict__ u_f32,
        const __bf16* __restrict__ u_bf,
        const float* __restrict__ vvec, const float* __restrict__ wvec,
        const int* __restrict__ ind, float* __restrict__ partials,
        int n_bs, int n_cls, int n_train) {
    __shared__ float red[4];
    __shared__ int pflag[32];
    const int tid  = threadIdx.x;
    const int lane = tid & 63;
    const int wid  = tid >> 6;
    const int c    = blockIdx.x * 4 + wid;
    const int t0   = blockIdx.y * 32;
    const int r    = lane & 31;
    const int h    = lane >> 5;
    const int row  = t0 + r;

    if (tid < 32) pflag[tid] = -1;

    // unconditional parallel loads (common case); clamp pad rows
    const int rc = (row < n_train) ? row : (n_train - 1);
    const float* __restrict__ ar = U + ((size_t)rc * n_cls + c) * CB + h * 8;
    float4 a0 = *(const float4*)(ar);
    float4 a1 = *(const float4*)(ar + 4);
    float Yv = Yb[(size_t)rc * n_cls + c];

    __syncthreads();                       // pflag init visible
    if (tid < n_bs) {
        unsigned rl = (unsigned)(ind[tid] - t0);
        if (rl < 32u) pflag[rl] = tid;     // rows distinct -> no conflict
    }
    __syncthreads();                       // patch flags complete

    const int pf = pflag[r];
    if (pf >= 0) {
        const float* __restrict__ src =
            u_f32 + ((size_t)pf * n_cls + c) * CB + h * 8;
        a0 = *(const float4*)(src);
        a1 = *(const float4*)(src + 4);
        Yv = y[(size_t)pf * n_cls + c];
    }
    if (row >= n_train) {
        a0 = make_float4(0.f, 0.f, 0.f, 0.f); a1 = a0; Yv = 0.f;
    }

    // side dots: sum_b s*ip -> Yv*(U_row.v), sum_b ip -> U_row.w
    const float* __restrict__ vp = vvec + (size_t)c * CB + h * 8;
    const float* __restrict__ wp = wvec + (size_t)c * CB + h * 8;
    float sv = a0.x*vp[0] + a0.y*vp[1] + a0.z*vp[2] + a0.w*vp[3]
             + a1.x*vp[4] + a1.y*vp[5] + a1.z*vp[6] + a1.w*vp[7];
    float sw = a0.x*wp[0] + a0.y*wp[1] + a0.z*wp[2] + a0.w*wp[3]
             + a1.x*wp[4] + a1.y*wp[5] + a1.z*wp[6] + a1.w*wp[7];
    const float sideS = Yv * sv;
    const float sideW = sw;

    bf16x8 A;
    A[0] = (__bf16)a0.x; A[1] = (__bf16)a0.y;
    A[2] = (__bf16)a0.z; A[3] = (__bf16)a0.w;
    A[4] = (__bf16)a1.x; A[5] = (__bf16)a1.y;
    A[6] = (__bf16)a1.z; A[7] = (__bf16)a1.w;

    const __bf16* __restrict__ ub = u_bf + (size_t)c * n_bs * CB;
    bf16x8 B[4];
    #pragma unroll
    for (int bt = 0; bt < 4; ++bt)
        B[bt] = *(const bf16x8*)(ub + (size_t)(bt * 32 + r) * CB + h * 8);

    f32x2 accA2 = {0.f, 0.f};   // packed sum |ip'|
    float pp    = 1.f;          // prod (1 + 2^-|ip'|) over 64 elems; <= 2^64
    const f32x2 one2 = {1.f, 1.f};
    f32x16 zc = {};
    #pragma unroll
    for (int bt = 0; bt < 4; ++bt) {
        f32x16 D = __builtin_amdgcn_mfma_f32_32x32x16_bf16(A, B[bt], zc, 0, 0, 0);
        f32x2 t[8];
        #pragma unroll
        for (int j2 = 0; j2 < 8; ++j2) {
            f32x2 d2;
            d2.x = D[2 * j2];
            d2.y = D[2 * j2 + 1];
            f32x2 ipa2 = __builtin_elementwise_max(d2, -d2);  // v_pk_max + neg mod
            accA2 += ipa2;                                    // v_pk_add
            f32x2 e2;
            e2.x = __builtin_amdgcn_exp2f(-ipa2.x);
            e2.y = __builtin_amdgcn_exp2f(-ipa2.y);
            t[j2] = e2 + one2;                                // v_pk_add
        }
        // packed product tree: 8 f32x2 -> 1 f32x2 -> scalar
        t[0] *= t[1]; t[2] *= t[3]; t[4] *= t[5]; t[6] *= t[7];
        t[0] *= t[2]; t[4] *= t[6];
        t[0] *= t[4];
        pp *= t[0].x * t[0].y;
    }
    float accL = __builtin_amdgcn_logf(pp);              // v_log_f32 = log2
    float accA = accA2.x + accA2.y;

    // combined per-lane contribution; pad rows contribute exactly LN2F each
    float contrib = LN2F * accL + (0.5f * LN2F) * accA + 0.5f * sideW - sideS;

    #pragma unroll
    for (int off = 32; off > 0; off >>= 1)
        contrib += __shfl_down(contrib, off, 64);
    if (lane == 0) red[wid] = contrib;
    __syncthreads();
    if (tid == 0) {
        int bid = blockIdx.y * gridDim.x + blockIdx.x;
        partials[bid] = red[0] + red[1] + red[2] + red[3];
    }
}

__global__ __launch_bounds__(256) void finalize_kernel(
        const float* __restrict__ partials, int nblk,
        const float* __restrict__ quant_partials, int n_quant,
        float* __restrict__ out, double pad_corr,
        double like_scale, double quant_scale) {
    double s = 0.0, q = 0.0;
    for (int i = threadIdx.x; i < nblk; i += 256) s += (double)partials[i];
    for (int i = threadIdx.x; i < n_quant; i += 256) q += (double)quant_partials[i];
    #pragma unroll
    for (int off = 32; off > 0; off >>= 1) {
        s += __shfl_down(s, off, 64);
        q += __shfl_down(q, off, 64);
    }
    __shared__ double dred[4][2];
    int lane = threadIdx.x & 63, wid = threadIdx.x >> 6;
    if (lane == 0) { dred[wid][0] = s; dred[wid][1] = q; }
    __syncthreads();
    if (threadIdx.x == 0) {
        double S = dred[0][0] + dred[1][0] + dred[2][0] + dred[3][0];
        double Q = dred[0][1] + dred[1][1] + dred[2][1] + dred[3][1];
        out[0] = (float)((S - pad_corr) * like_scale + Q * quant_scale);
    }
}

extern "C" void kernel_launch(void* const* d_in, const int* in_sizes, int n_in,
                              void* d_out, int out_size, void* d_ws, size_t ws_size,
                              hipStream_t stream) {
    const float* u   = (const float*)d_in[0];
    const float* y   = (const float*)d_in[1];
    const int*   ind = (const int*)d_in[2];
    const float* U   = (const float*)d_in[3];
    const float* Yb  = (const float*)d_in[4];
    const float* w_D = (const float*)d_in[5];

    const int n_bs    = in_sizes[2];             // 128
    const int bit     = in_sizes[0] / n_bs;      // 48
    const int n_cls   = in_sizes[1] / n_bs;      // 100
    const int n_train = in_sizes[4] / n_cls;     // 10000

    const int totalU = n_bs * n_cls * CB;
    const int nub    = (totalU + 255) / 256;     // 800
    const int ntile  = (n_train + 31) / 32;      // 313
    const int gx     = (n_cls + 3) / 4;          // 25
    const int nblk   = ntile * gx;

    char* ws = (char*)d_ws;
    size_t off = 0;
    float* u_f32 = (float*)(ws + off);          off += (size_t)totalU * 4;
    __bf16* u_bf = (__bf16*)(ws + off);         off += (size_t)totalU * 2;
    off = (off + 15) & ~(size_t)15;
    float* vvec = (float*)(ws + off);           off += (size_t)n_cls * CB * 4;
    float* wvec = (float*)(ws + off);           off += (size_t)n_cls * CB * 4;
    float* quant_partials = (float*)(ws + off); off += (size_t)nub * 4;
    off = (off + 15) & ~(size_t)15;
    float* partials = (float*)(ws + off);       off += (size_t)nblk * 4;

    prep_kernel<<<nub + n_cls, 256, 0, stream>>>(
        u, y, w_D, u_f32, u_bf, quant_partials, vvec, wvec,
        n_bs, bit, n_cls, nub);

    loss_main_mfma<<<dim3(gx, ntile), 256, 0, stream>>>(
        y, U, Yb, u_f32, u_bf, vvec, wvec, ind, partials,
        n_bs, n_cls, n_train);

    const double ln2 = 0.6931471805599453;
    const double n_pad = (double)((long long)(ntile * 32 - n_train) *
                                  (long long)n_bs * (long long)n_cls);
    const double pad_corr    = ln2 * n_pad;
    const double like_scale  = 1.0 / ((double)n_bs * n_train * n_cls);
    const double quant_scale = (double)ALPHA / (double)totalU;

    finalize_kernel<<<1, 256, 0, stream>>>(partials, nblk, quant_partials, nub,
                                           (float*)d_out, pad_corr,
                                           like_scale, quant_scale);
}

// Round 11
// 55.435 us; speedup vs baseline: 3.6310x; 1.1698x over previous
//
#include <hip/hip_runtime.h>
#include <math.h>

#define CB 16          // class_bit
#define ALPHA 0.1f
#define LOG2E 1.4426950408889634f
#define LN2F  0.6931471805599453f

typedef __bf16 bf16x8 __attribute__((ext_vector_type(8)));
typedef float  f32x16 __attribute__((ext_vector_type(16)));
typedef float  f32x2  __attribute__((ext_vector_type(2)));

__device__ inline float block_reduce_256(float v, float* red) {
    #pragma unroll
    for (int off = 32; off > 0; off >>= 1) v += __shfl_down(v, off, 64);
    int lane = threadIdx.x & 63;
    int wid  = threadIdx.x >> 6;
    if (lane == 0) red[wid] = v;
    __syncthreads();
    float s = 0.f;
    if (threadIdx.x == 0) {
        int nw = blockDim.x >> 6;
        for (int w = 0; w < nw; ++w) s += red[w];
    }
    return s;
}

// Fused prep (unchanged from Round 8):
//  blocks [0, nub):        u_ = einsum -> u_f32 / u_bf(scaled log2e) / quant partials
//  blocks [nub, nub+n_cls): vvec/wvec from u,y,w_D directly
__global__ __launch_bounds__(256) void prep_kernel(
        const float* __restrict__ u, const float* __restrict__ y,
        const float* __restrict__ w_D,
        float* __restrict__ u_f32, __bf16* __restrict__ u_bf,
        float* __restrict__ quant_partials,
        float* __restrict__ vvec, float* __restrict__ wvec,
        int n_bs, int bit, int n_cls, int nub) {
    __shared__ float red[4];
    __shared__ float yus[4][64];
    __shared__ float sus[4][64];
    if ((int)blockIdx.x < nub) {
        int idx = blockIdx.x * 256 + threadIdx.x;
        int total = n_bs * n_cls * CB;
        float q = 0.f;
        if (idx < total) {
            int d = idx & (CB - 1);
            int c = (idx / CB) % n_cls;
            int b = idx / (CB * n_cls);
            const float* __restrict__ ur = u + (size_t)b * bit;
            const float* __restrict__ w  = w_D + (size_t)c * bit * CB + d;
            float s = 0.f;
            for (int k = 0; k < bit; ++k) s = fmaf(ur[k], w[k * CB], s);
            u_f32[idx] = s;
            u_bf[((size_t)c * n_bs + b) * CB + d] = (__bf16)(s * LOG2E);
            float sgn = (s > 0.f) ? 1.f : ((s < 0.f) ? -1.f : 0.f);
            float dd = s - sgn;
            q = dd * dd;
        }
        float bs = block_reduce_256(q, red);
        if (threadIdx.x == 0) quant_partials[blockIdx.x] = bs;
    } else {
        const int c  = blockIdx.x - nub;
        const int kk = threadIdx.x & 63;       // k index (bit <= 64)
        const int sl = threadIdx.x >> 6;       // 4 b-slices
        float yv = 0.f, sv = 0.f;
        if (kk < bit) {
            const int bpp = n_bs >> 2;
            for (int b = sl * bpp; b < (sl + 1) * bpp; ++b) {
                float uv = u[(size_t)b * bit + kk];
                sv += uv;
                yv = fmaf(y[(size_t)b * n_cls + c], uv, yv);
            }
        }
        yus[sl][kk] = yv; sus[sl][kk] = sv;
        __syncthreads();
        if (sl == 0 && kk < bit) {
            yus[0][kk] = yus[0][kk] + yus[1][kk] + yus[2][kk] + yus[3][kk];
            sus[0][kk] = sus[0][kk] + sus[1][kk] + sus[2][kk] + sus[3][kk];
        }
        __syncthreads();
        if (threadIdx.x < CB) {
            const int d = threadIdx.x;
            const float* __restrict__ wdc = w_D + (size_t)c * bit * CB + d;
            float v = 0.f, w = 0.f;
            for (int k = 0; k < bit; ++k) {
                float wv = wdc[k * CB];
                v = fmaf(yus[0][k], wv, v);
                w = fmaf(sus[0][k], wv, w);
            }
            vvec[(size_t)c * CB + d] = v;
            wvec[(size_t)c * CB + d] = w;
        }
    }
}

// One block = 32-row t-tile x 4 classes (one class per wave, 4 MFMAs/wave).
// Exact R8 structure (51.2 us proven). Epilogue: packed-f32 pairs with a
// SINGLE running f32x2 product accumulator (no tree array -> minimal
// liveness; Round 10 lesson: t[8] array cost 16 VGPR -> occupancy collapse).
// Each pp2 component accumulates 32 factors in (1,2] -> <= 2^32, f32-safe.
// No fences, no cross-block sync (Round 6/7 lesson); no deep per-thread
// pipelining (Round 9 lesson: spills to scratch).
__global__ __launch_bounds__(256, 4) void loss_main_mfma(
        const float* __restrict__ y, const float* __restrict__ U,
        const float* __restrict__ Yb, const float* __restrict__ u_f32,
        const __bf16* __restrict__ u_bf,
        const float* __restrict__ vvec, const float* __restrict__ wvec,
        const int* __restrict__ ind, float* __restrict__ partials,
        int n_bs, int n_cls, int n_train) {
    __shared__ float red[4];
    __shared__ int pflag[32];
    const int tid  = threadIdx.x;
    const int lane = tid & 63;
    const int wid  = tid >> 6;
    const int c    = blockIdx.x * 4 + wid;
    const int t0   = blockIdx.y * 32;
    const int r    = lane & 31;
    const int h    = lane >> 5;
    const int row  = t0 + r;

    if (tid < 32) pflag[tid] = -1;

    // unconditional parallel loads (common case); clamp pad rows
    const int rc = (row < n_train) ? row : (n_train - 1);
    const float* __restrict__ ar = U + ((size_t)rc * n_cls + c) * CB + h * 8;
    float4 a0 = *(const float4*)(ar);
    float4 a1 = *(const float4*)(ar + 4);
    float Yv = Yb[(size_t)rc * n_cls + c];

    __syncthreads();                       // pflag init visible
    if (tid < n_bs) {
        unsigned rl = (unsigned)(ind[tid] - t0);
        if (rl < 32u) pflag[rl] = tid;     // rows distinct -> no conflict
    }
    __syncthreads();                       // patch flags complete

    const int pf = pflag[r];
    if (pf >= 0) {
        const float* __restrict__ src =
            u_f32 + ((size_t)pf * n_cls + c) * CB + h * 8;
        a0 = *(const float4*)(src);
        a1 = *(const float4*)(src + 4);
        Yv = y[(size_t)pf * n_cls + c];
    }
    if (row >= n_train) {
        a0 = make_float4(0.f, 0.f, 0.f, 0.f); a1 = a0; Yv = 0.f;
    }

    // side dots: sum_b s*ip -> Yv*(U_row.v), sum_b ip -> U_row.w
    const float* __restrict__ vp = vvec + (size_t)c * CB + h * 8;
    const float* __restrict__ wp = wvec + (size_t)c * CB + h * 8;
    float sv = a0.x*vp[0] + a0.y*vp[1] + a0.z*vp[2] + a0.w*vp[3]
             + a1.x*vp[4] + a1.y*vp[5] + a1.z*vp[6] + a1.w*vp[7];
    float sw = a0.x*wp[0] + a0.y*wp[1] + a0.z*wp[2] + a0.w*wp[3]
             + a1.x*wp[4] + a1.y*wp[5] + a1.z*wp[6] + a1.w*wp[7];
    const float sideS = Yv * sv;
    const float sideW = sw;

    bf16x8 A;
    A[0] = (__bf16)a0.x; A[1] = (__bf16)a0.y;
    A[2] = (__bf16)a0.z; A[3] = (__bf16)a0.w;
    A[4] = (__bf16)a1.x; A[5] = (__bf16)a1.y;
    A[6] = (__bf16)a1.z; A[7] = (__bf16)a1.w;

    const __bf16* __restrict__ ub = u_bf + (size_t)c * n_bs * CB;
    bf16x8 B[4];
    #pragma unroll
    for (int bt = 0; bt < 4; ++bt)
        B[bt] = *(const bf16x8*)(ub + (size_t)(bt * 32 + r) * CB + h * 8);

    f32x2 accA2 = {0.f, 0.f};     // packed sum |ip'|
    f32x2 pp2   = {1.f, 1.f};     // packed running product (32 factors/lane each)
    const f32x2 one2 = {1.f, 1.f};
    f32x16 zc = {};
    #pragma unroll
    for (int bt = 0; bt < 4; ++bt) {
        f32x16 D = __builtin_amdgcn_mfma_f32_32x32x16_bf16(A, B[bt], zc, 0, 0, 0);
        #pragma unroll
        for (int j2 = 0; j2 < 8; ++j2) {
            f32x2 d2;
            d2.x = D[2 * j2];
            d2.y = D[2 * j2 + 1];
            f32x2 ipa2 = __builtin_elementwise_max(d2, -d2);  // v_pk_max + neg
            accA2 += ipa2;                                    // v_pk_add
            f32x2 e2;
            e2.x = __builtin_amdgcn_exp2f(-ipa2.x);           // neg = src mod
            e2.y = __builtin_amdgcn_exp2f(-ipa2.y);
            pp2 *= (e2 + one2);                               // v_pk_add + v_pk_mul
        }
    }
    float pp   = pp2.x * pp2.y;                  // <= 2^64, f32-safe
    float accL = __builtin_amdgcn_logf(pp);      // v_log_f32 = log2
    float accA = accA2.x + accA2.y;

    // combined per-lane contribution; pad rows contribute exactly LN2F each
    float contrib = LN2F * accL + (0.5f * LN2F) * accA + 0.5f * sideW - sideS;

    #pragma unroll
    for (int off = 32; off > 0; off >>= 1)
        contrib += __shfl_down(contrib, off, 64);
    if (lane == 0) red[wid] = contrib;
    __syncthreads();
    if (tid == 0) {
        int bid = blockIdx.y * gridDim.x + blockIdx.x;
        partials[bid] = red[0] + red[1] + red[2] + red[3];
    }
}

__global__ __launch_bounds__(256) void finalize_kernel(
        const float* __restrict__ partials, int nblk,
        const float* __restrict__ quant_partials, int n_quant,
        float* __restrict__ out, double pad_corr,
        double like_scale, double quant_scale) {
    double s = 0.0, q = 0.0;
    for (int i = threadIdx.x; i < nblk; i += 256) s += (double)partials[i];
    for (int i = threadIdx.x; i < n_quant; i += 256) q += (double)quant_partials[i];
    #pragma unroll
    for (int off = 32; off > 0; off >>= 1) {
        s += __shfl_down(s, off, 64);
        q += __shfl_down(q, off, 64);
    }
    __shared__ double dred[4][2];
    int lane = threadIdx.x & 63, wid = threadIdx.x >> 6;
    if (lane == 0) { dred[wid][0] = s; dred[wid][1] = q; }
    __syncthreads();
    if (threadIdx.x == 0) {
        double S = dred[0][0] + dred[1][0] + dred[2][0] + dred[3][0];
        double Q = dred[0][1] + dred[1][1] + dred[2][1] + dred[3][1];
        out[0] = (float)((S - pad_corr) * like_scale + Q * quant_scale);
    }
}

extern "C" void kernel_launch(void* const* d_in, const int* in_sizes, int n_in,
                              void* d_out, int out_size, void* d_ws, size_t ws_size,
                              hipStream_t stream) {
    const float* u   = (const float*)d_in[0];
    const float* y   = (const float*)d_in[1];
    const int*   ind = (const int*)d_in[2];
    const float* U   = (const float*)d_in[3];
    const float* Yb  = (const float*)d_in[4];
    const float* w_D = (const float*)d_in[5];

    const int n_bs    = in_sizes[2];             // 128
    const int bit     = in_sizes[0] / n_bs;      // 48
    const int n_cls   = in_sizes[1] / n_bs;      // 100
    const int n_train = in_sizes[4] / n_cls;     // 10000

    const int totalU = n_bs * n_cls * CB;
    const int nub    = (totalU + 255) / 256;     // 800
    const int ntile  = (n_train + 31) / 32;      // 313
    const int gx     = (n_cls + 3) / 4;          // 25
    const int nblk   = ntile * gx;

    char* ws = (char*)d_ws;
    size_t off = 0;
    float* u_f32 = (float*)(ws + off);          off += (size_t)totalU * 4;
    __bf16* u_bf = (__bf16*)(ws + off);         off += (size_t)totalU * 2;
    off = (off + 15) & ~(size_t)15;
    float* vvec = (float*)(ws + off);           off += (size_t)n_cls * CB * 4;
    float* wvec = (float*)(ws + off);           off += (size_t)n_cls * CB * 4;
    float* quant_partials = (float*)(ws + off); off += (size_t)nub * 4;
    off = (off + 15) & ~(size_t)15;
    float* partials = (float*)(ws + off);       off += (size_t)nblk * 4;

    prep_kernel<<<nub + n_cls, 256, 0, stream>>>(
        u, y, w_D, u_f32, u_bf, quant_partials, vvec, wvec,
        n_bs, bit, n_cls, nub);

    loss_main_mfma<<<dim3(gx, ntile), 256, 0, stream>>>(
        y, U, Yb, u_f32, u_bf, vvec, wvec, ind, partials,
        n_bs, n_cls, n_train);

    const double ln2 = 0.6931471805599453;
    const double n_pad = (double)((long long)(ntile * 32 - n_train) *
                                  (long long)n_bs * (long long)n_cls);
    const double pad_corr    = ln2 * n_pad;
    const double like_scale  = 1.0 / ((double)n_bs * n_train * n_cls);
    const double quant_scale = (double)ALPHA / (double)totalU;

    finalize_kernel<<<1, 256, 0, stream>>>(partials, nblk, quant_partials, nub,
                                           (float*)d_out, pad_corr,
                                           like_scale, quant_scale);
}

// Round 12
// 51.674 us; speedup vs baseline: 3.8953x; 1.0728x over previous
//
#include <hip/hip_runtime.h>
#include <math.h>

#define CB 16          // class_bit
#define ALPHA 0.1f
#define LOG2E 1.4426950408889634f
#define LN2F  0.6931471805599453f
#define MAXW 8         // max t-tiles per block (host sets GY = ceil(ntile/8))

typedef __bf16 bf16x8 __attribute__((ext_vector_type(8)));
typedef float  f32x16 __attribute__((ext_vector_type(16)));

__device__ inline float block_reduce_256(float v, float* red) {
    #pragma unroll
    for (int off = 32; off > 0; off >>= 1) v += __shfl_down(v, off, 64);
    int lane = threadIdx.x & 63;
    int wid  = threadIdx.x >> 6;
    if (lane == 0) red[wid] = v;
    __syncthreads();
    float s = 0.f;
    if (threadIdx.x == 0) {
        int nw = blockDim.x >> 6;
        for (int w = 0; w < nw; ++w) s += red[w];
    }
    return s;
}

// Fused prep (unchanged, proven):
//  blocks [0, nub):        u_ = einsum -> u_f32 / u_bf(scaled log2e) / quant partials
//  blocks [nub, nub+n_cls): vvec/wvec from u,y,w_D directly
__global__ __launch_bounds__(256) void prep_kernel(
        const float* __restrict__ u, const float* __restrict__ y,
        const float* __restrict__ w_D,
        float* __restrict__ u_f32, __bf16* __restrict__ u_bf,
        float* __restrict__ quant_partials,
        float* __restrict__ vvec, float* __restrict__ wvec,
        int n_bs, int bit, int n_cls, int nub) {
    __shared__ float red[4];
    __shared__ float yus[4][64];
    __shared__ float sus[4][64];
    if ((int)blockIdx.x < nub) {
        int idx = blockIdx.x * 256 + threadIdx.x;
        int total = n_bs * n_cls * CB;
        float q = 0.f;
        if (idx < total) {
            int d = idx & (CB - 1);
            int c = (idx / CB) % n_cls;
            int b = idx / (CB * n_cls);
            const float* __restrict__ ur = u + (size_t)b * bit;
            const float* __restrict__ w  = w_D + (size_t)c * bit * CB + d;
            float s = 0.f;
            for (int k = 0; k < bit; ++k) s = fmaf(ur[k], w[k * CB], s);
            u_f32[idx] = s;
            u_bf[((size_t)c * n_bs + b) * CB + d] = (__bf16)(s * LOG2E);
            float sgn = (s > 0.f) ? 1.f : ((s < 0.f) ? -1.f : 0.f);
            float dd = s - sgn;
            q = dd * dd;
        }
        float bs = block_reduce_256(q, red);
        if (threadIdx.x == 0) quant_partials[blockIdx.x] = bs;
    } else {
        const int c  = blockIdx.x - nub;
        const int kk = threadIdx.x & 63;       // k index (bit <= 64)
        const int sl = threadIdx.x >> 6;       // 4 b-slices
        float yv = 0.f, sv = 0.f;
        if (kk < bit) {
            const int bpp = n_bs >> 2;
            for (int b = sl * bpp; b < (sl + 1) * bpp; ++b) {
                float uv = u[(size_t)b * bit + kk];
                sv += uv;
                yv = fmaf(y[(size_t)b * n_cls + c], uv, yv);
            }
        }
        yus[sl][kk] = yv; sus[sl][kk] = sv;
        __syncthreads();
        if (sl == 0 && kk < bit) {
            yus[0][kk] = yus[0][kk] + yus[1][kk] + yus[2][kk] + yus[3][kk];
            sus[0][kk] = sus[0][kk] + sus[1][kk] + sus[2][kk] + sus[3][kk];
        }
        __syncthreads();
        if (threadIdx.x < CB) {
            const int d = threadIdx.x;
            const float* __restrict__ wdc = w_D + (size_t)c * bit * CB + d;
            float v = 0.f, w = 0.f;
            for (int k = 0; k < bit; ++k) {
                float wv = wdc[k * CB];
                v = fmaf(yus[0][k], wv, v);
                w = fmaf(sus[0][k], wv, w);
            }
            vvec[(size_t)c * CB + d] = v;
            wvec[(size_t)c * CB + d] = w;
        }
    }
}

// Grid-stride loss kernel: grid (gx=25, GY); block (bx,by) handles tiles
// {by, by+GY, by+2GY, ...} (< ntile) for classes 4bx..4bx+3 (one per wave).
// Hoisted per block: B-frags, vvec/wvec, ALL pflag windows (one barrier pair).
// Per-tile loop: ZERO barriers; R8's proven scalar epilogue (product-of-16
// log amortization). Per-wave partials (no block reduce, no final sync).
// No fences (R6/7 lesson), no cross-tile pipelining (#pragma unroll 1,
// R9 lesson), minimal live state (R10 lesson).
__global__ __launch_bounds__(256, 4) void loss_main_mfma(
        const float* __restrict__ y, const float* __restrict__ U,
        const float* __restrict__ Yb, const float* __restrict__ u_f32,
        const __bf16* __restrict__ u_bf,
        const float* __restrict__ vvec, const float* __restrict__ wvec,
        const int* __restrict__ ind, float* __restrict__ partials,
        int n_bs, int n_cls, int n_train, int ntile, int GY) {
    __shared__ int pflag[MAXW * 32];
    const int tid  = threadIdx.x;
    const int lane = tid & 63;
    const int wid  = tid >> 6;
    const int c    = blockIdx.x * 4 + wid;
    const int by   = blockIdx.y;
    const int r    = lane & 31;
    const int h    = lane >> 5;
    const int nw   = (ntile - by + GY - 1) / GY;   // tiles this block owns (>=1)

    for (int i = tid; i < MAXW * 32; i += 256) pflag[i] = -1;
    __syncthreads();
    if (tid < n_bs) {
        int t = ind[tid];
        for (int w = 0; w < nw; ++w) {
            unsigned rl = (unsigned)(t - (by + w * GY) * 32);
            if (rl < 32u) pflag[w * 32 + rl] = tid;   // rows distinct
        }
    }
    __syncthreads();                       // pflag complete; read-only after

    // hoisted: B fragments + vvec/wvec (class-invariant across tiles)
    const __bf16* __restrict__ ub = u_bf + (size_t)c * n_bs * CB;
    bf16x8 B[4];
    #pragma unroll
    for (int bt = 0; bt < 4; ++bt)
        B[bt] = *(const bf16x8*)(ub + (size_t)(bt * 32 + r) * CB + h * 8);
    const float* __restrict__ vp = vvec + (size_t)c * CB + h * 8;
    const float* __restrict__ wp = wvec + (size_t)c * CB + h * 8;
    float4 vp0 = *(const float4*)(vp);
    float4 vp1 = *(const float4*)(vp + 4);
    float4 wp0 = *(const float4*)(wp);
    float4 wp1 = *(const float4*)(wp + 4);

    float acc = 0.f;
    f32x16 zc = {};
    #pragma unroll 1
    for (int w = 0; w < nw; ++w) {
        const int t0  = (by + w * GY) * 32;
        const int row = t0 + r;
        const int rc  = (row < n_train) ? row : (n_train - 1);
        const float* __restrict__ ar = U + ((size_t)rc * n_cls + c) * CB + h * 8;
        float4 a0 = *(const float4*)(ar);
        float4 a1 = *(const float4*)(ar + 4);
        float Yv = Yb[(size_t)rc * n_cls + c];

        const int pf = pflag[w * 32 + r];
        if (pf >= 0) {
            const float* __restrict__ src =
                u_f32 + ((size_t)pf * n_cls + c) * CB + h * 8;
            a0 = *(const float4*)(src);
            a1 = *(const float4*)(src + 4);
            Yv = y[(size_t)pf * n_cls + c];
        }
        if (row >= n_train) {
            a0 = make_float4(0.f, 0.f, 0.f, 0.f); a1 = a0; Yv = 0.f;
        }

        // side dots: sum_b s*ip -> Yv*(U_row.v), sum_b ip -> U_row.w
        float sv = a0.x*vp0.x + a0.y*vp0.y + a0.z*vp0.z + a0.w*vp0.w
                 + a1.x*vp1.x + a1.y*vp1.y + a1.z*vp1.z + a1.w*vp1.w;
        float sw = a0.x*wp0.x + a0.y*wp0.y + a0.z*wp0.z + a0.w*wp0.w
                 + a1.x*wp1.x + a1.y*wp1.y + a1.z*wp1.z + a1.w*wp1.w;

        bf16x8 A;
        A[0] = (__bf16)a0.x; A[1] = (__bf16)a0.y;
        A[2] = (__bf16)a0.z; A[3] = (__bf16)a0.w;
        A[4] = (__bf16)a1.x; A[5] = (__bf16)a1.y;
        A[6] = (__bf16)a1.z; A[7] = (__bf16)a1.w;

        float accA = 0.f;    // sum |ip'| this tile
        float pp   = 1.f;    // prod (1 + 2^-|ip'|), 64 factors in (1,2] <= 2^64
        #pragma unroll
        for (int bt = 0; bt < 4; ++bt) {
            f32x16 D = __builtin_amdgcn_mfma_f32_32x32x16_bf16(A, B[bt], zc,
                                                               0, 0, 0);
            float a[16];
            #pragma unroll
            for (int j = 0; j < 16; ++j) {
                float ipa = fabsf(D[j]);
                a[j] = 1.0f + __builtin_amdgcn_exp2f(-ipa);
                accA += ipa;
            }
            #pragma unroll
            for (int s = 1; s < 16; s <<= 1)
                #pragma unroll
                for (int j = 0; j < 16; j += 2 * s) a[j] *= a[j + s];
            pp *= a[0];
        }
        float accL = __builtin_amdgcn_logf(pp);   // v_log_f32 = log2
        // pad rows contribute exactly LN2F each (pp *= 2), host-corrected
        acc += LN2F * accL + (0.5f * LN2F) * accA + 0.5f * sw - Yv * sv;
    }

    // per-wave reduction only; no block reduce, no sync
    #pragma unroll
    for (int off = 32; off > 0; off >>= 1)
        acc += __shfl_down(acc, off, 64);
    if (lane == 0) {
        int bid = by * gridDim.x + blockIdx.x;
        partials[bid * 4 + wid] = acc;
    }
}

__global__ __launch_bounds__(256) void finalize_kernel(
        const float* __restrict__ partials, int nblk,
        const float* __restrict__ quant_partials, int n_quant,
        float* __restrict__ out, double pad_corr,
        double like_scale, double quant_scale) {
    double s = 0.0, q = 0.0;
    for (int i = threadIdx.x; i < nblk; i += 256) s += (double)partials[i];
    for (int i = threadIdx.x; i < n_quant; i += 256) q += (double)quant_partials[i];
    #pragma unroll
    for (int off = 32; off > 0; off >>= 1) {
        s += __shfl_down(s, off, 64);
        q += __shfl_down(q, off, 64);
    }
    __shared__ double dred[4][2];
    int lane = threadIdx.x & 63, wid = threadIdx.x >> 6;
    if (lane == 0) { dred[wid][0] = s; dred[wid][1] = q; }
    __syncthreads();
    if (threadIdx.x == 0) {
        double S = dred[0][0] + dred[1][0] + dred[2][0] + dred[3][0];
        double Q = dred[0][1] + dred[1][1] + dred[2][1] + dred[3][1];
        out[0] = (float)((S - pad_corr) * like_scale + Q * quant_scale);
    }
}

extern "C" void kernel_launch(void* const* d_in, const int* in_sizes, int n_in,
                              void* d_out, int out_size, void* d_ws, size_t ws_size,
                              hipStream_t stream) {
    const float* u   = (const float*)d_in[0];
    const float* y   = (const float*)d_in[1];
    const int*   ind = (const int*)d_in[2];
    const float* U   = (const float*)d_in[3];
    const float* Yb  = (const float*)d_in[4];
    const float* w_D = (const float*)d_in[5];

    const int n_bs    = in_sizes[2];             // 128
    const int bit     = in_sizes[0] / n_bs;      // 48
    const int n_cls   = in_sizes[1] / n_bs;      // 100
    const int n_train = in_sizes[4] / n_cls;     // 10000

    const int totalU = n_bs * n_cls * CB;
    const int nub    = (totalU + 255) / 256;     // 800
    const int ntile  = (n_train + 31) / 32;      // 313
    const int GY     = (ntile + MAXW - 1) / MAXW; // 40
    const int gx     = (n_cls + 3) / 4;          // 25
    const int nblk   = GY * gx;                  // 1000 blocks
    const int npart  = nblk * 4;                 // per-wave partials

    char* ws = (char*)d_ws;
    size_t off = 0;
    float* u_f32 = (float*)(ws + off);          off += (size_t)totalU * 4;
    __bf16* u_bf = (__bf16*)(ws + off);         off += (size_t)totalU * 2;
    off = (off + 15) & ~(size_t)15;
    float* vvec = (float*)(ws + off);           off += (size_t)n_cls * CB * 4;
    float* wvec = (float*)(ws + off);           off += (size_t)n_cls * CB * 4;
    float* quant_partials = (float*)(ws + off); off += (size_t)nub * 4;
    off = (off + 15) & ~(size_t)15;
    float* partials = (float*)(ws + off);       off += (size_t)npart * 4;

    prep_kernel<<<nub + n_cls, 256, 0, stream>>>(
        u, y, w_D, u_f32, u_bf, quant_partials, vvec, wvec,
        n_bs, bit, n_cls, nub);

    loss_main_mfma<<<dim3(gx, GY), 256, 0, stream>>>(
        y, U, Yb, u_f32, u_bf, vvec, wvec, ind, partials,
        n_bs, n_cls, n_train, ntile, GY);

    const double ln2 = 0.6931471805599453;
    const double n_pad = (double)((long long)(ntile * 32 - n_train) *
                                  (long long)n_bs * (long long)n_cls);
    const double pad_corr    = ln2 * n_pad;
    const double like_scale  = 1.0 / ((double)n_bs * n_train * n_cls);
    const double quant_scale = (double)ALPHA / (double)totalU;

    finalize_kernel<<<1, 256, 0, stream>>>(partials, npart, quant_partials, nub,
                                           (float*)d_out, pad_corr,
                                           like_scale, quant_scale);
}

// Round 13
// 49.409 us; speedup vs baseline: 4.0738x; 1.0458x over previous
//
#include <hip/hip_runtime.h>
#include <math.h>

#define CB 16          // class_bit
#define ALPHA 0.1f
#define LOG2E 1.4426950408889634f
#define LN2F  0.6931471805599453f
#define MAXW 8         // max t-tiles per block
#define N_BS 128       // batch size (fixed by problem)
#define BIT  48        // code length (fixed by problem)
#define UPAD 52        // u row pitch in LDS floats (16B-aligned, spreads banks)

typedef __bf16 bf16x8 __attribute__((ext_vector_type(8)));
typedef float  f32x16 __attribute__((ext_vector_type(16)));

// Single fused main kernel: each block recomputes the u_ slice it needs
// (4 classes x 128 b x 16 d dots, K=48) from u/w_D staged in LDS -- no prep
// kernel, no u_f32/u_bf HBM round-trip, no global sync. Everything after
// phase 0 is byte-identical to the proven R12 tile loop.
// Lessons kept: no fences (R6/7), no cross-tile pipelining (R9), minimal
// live state (R10), scalar product-tree epilogue (R11).
__global__ __launch_bounds__(256, 4) void loss_fused(
        const float* __restrict__ u, const float* __restrict__ y,
        const float* __restrict__ w_D,
        const float* __restrict__ U, const float* __restrict__ Yb,
        const int* __restrict__ ind,
        float* __restrict__ partials, float* __restrict__ quant_partials,
        int n_cls, int n_train, int ntile, int GY) {
    __shared__ float smf[N_BS * UPAD + 4 * BIT * CB];  // 38,912 B, reused
    __shared__ int pflag[MAXW * 32];                   // 1,024 B
    float* u_lds   = smf;                    // [N_BS][UPAD]      (phase 0)
    float* wd_lds  = smf + N_BS * UPAD;      // [4][BIT][CB]      (phase 0)
    float* u_slice = smf;                    // [4][N_BS][CB]     (after sync2)

    const int tid  = threadIdx.x;
    const int lane = tid & 63;
    const int wid  = tid >> 6;
    const int bx   = blockIdx.x;
    const int by   = blockIdx.y;
    const int c    = bx * 4 + wid;           // class for this wave
    const int r    = lane & 31;
    const int h    = lane >> 5;
    const int nw   = (ntile - by + GY - 1) / GY;

    // ---- stage u + w_D slice into LDS; init pflag ----
    pflag[tid] = -1;                          // MAXW*32 == 256 == blockDim
    #pragma unroll
    for (int it = 0; it < N_BS * (BIT / 4) / 256; ++it) {   // 6 float4 each
        int f = it * 256 + tid;
        int b = f / (BIT / 4), k4 = f % (BIT / 4);
        *(float4*)&u_lds[b * UPAD + k4 * 4] =
            *(const float4*)&u[(size_t)b * BIT + k4 * 4];
    }
    #pragma unroll
    for (int it = 0; it < 4 * BIT * (CB / 4) / 256; ++it) { // 3 float4 each
        int f = it * 256 + tid;
        int cc = f / (BIT * CB / 4), rest = f % (BIT * CB / 4);
        *(float4*)&wd_lds[cc * BIT * CB + rest * 4] =
            *(const float4*)&w_D[(size_t)(bx * 4 + cc) * BIT * CB + rest * 4];
    }
    __syncthreads();                          // sync1: staging + pflag init

    // ---- pflag build (rows distinct -> direct store, no atomics) ----
    if (tid < N_BS) {
        int t = ind[tid];
        for (int w = 0; w < nw; ++w) {
            unsigned rl = (unsigned)(t - (by + w * GY) * 32);
            if (rl < 32u) pflag[w * 32 + rl] = tid;
        }
    }

    // ---- phase 0: per-lane u_ slice: accX[j] = u_[X*32+r][c][h*8+j] ----
    float acc0[8] = {0,0,0,0,0,0,0,0};
    float acc1[8] = {0,0,0,0,0,0,0,0};
    float acc2[8] = {0,0,0,0,0,0,0,0};
    float acc3[8] = {0,0,0,0,0,0,0,0};
    {
        const float* __restrict__ wdc = wd_lds + wid * BIT * CB + h * 8;
        for (int k4 = 0; k4 < BIT / 4; ++k4) {
            float4 ub0 = *(const float4*)&u_lds[(0 * 32 + r) * UPAD + k4 * 4];
            float4 ub1 = *(const float4*)&u_lds[(1 * 32 + r) * UPAD + k4 * 4];
            float4 ub2 = *(const float4*)&u_lds[(2 * 32 + r) * UPAD + k4 * 4];
            float4 ub3 = *(const float4*)&u_lds[(3 * 32 + r) * UPAD + k4 * 4];
            #pragma unroll
            for (int kk = 0; kk < 4; ++kk) {
                const float* wrow = wdc + (k4 * 4 + kk) * CB;
                float w8[8];
                float4 wa = *(const float4*)(wrow);
                float4 wb = *(const float4*)(wrow + 4);
                w8[0]=wa.x; w8[1]=wa.y; w8[2]=wa.z; w8[3]=wa.w;
                w8[4]=wb.x; w8[5]=wb.y; w8[6]=wb.z; w8[7]=wb.w;
                float s0 = (&ub0.x)[kk], s1 = (&ub1.x)[kk];
                float s2 = (&ub2.x)[kk], s3 = (&ub3.x)[kk];
                #pragma unroll
                for (int j = 0; j < 8; ++j) {
                    acc0[j] = fmaf(s0, w8[j], acc0[j]);
                    acc1[j] = fmaf(s1, w8[j], acc1[j]);
                    acc2[j] = fmaf(s2, w8[j], acc2[j]);
                    acc3[j] = fmaf(s3, w8[j], acc3[j]);
                }
            }
        }
    }

    // ---- quantization partial (each element exactly once: by==0 only) ----
    if (by == 0) {
        float q = 0.f;
        #pragma unroll
        for (int j = 0; j < 8; ++j) {
            float v, sgn, d;
            v = acc0[j]; sgn = (v>0.f)?1.f:((v<0.f)?-1.f:0.f); d = v-sgn; q = fmaf(d,d,q);
            v = acc1[j]; sgn = (v>0.f)?1.f:((v<0.f)?-1.f:0.f); d = v-sgn; q = fmaf(d,d,q);
            v = acc2[j]; sgn = (v>0.f)?1.f:((v<0.f)?-1.f:0.f); d = v-sgn; q = fmaf(d,d,q);
            v = acc3[j]; sgn = (v>0.f)?1.f:((v<0.f)?-1.f:0.f); d = v-sgn; q = fmaf(d,d,q);
        }
        #pragma unroll
        for (int off = 32; off > 0; off >>= 1) q += __shfl_down(q, off, 64);
        if (lane == 0) quant_partials[bx * 4 + wid] = q;
    }

    // ---- vvec/wvec for this class, in registers (shfl_xor reduce over r) ----
    float ypc0 = y[(size_t)(0 * 32 + r) * n_cls + c];
    float ypc1 = y[(size_t)(1 * 32 + r) * n_cls + c];
    float ypc2 = y[(size_t)(2 * 32 + r) * n_cls + c];
    float ypc3 = y[(size_t)(3 * 32 + r) * n_cls + c];
    float vv[8], ww[8];
    #pragma unroll
    for (int j = 0; j < 8; ++j) {
        ww[j] = acc0[j] + acc1[j] + acc2[j] + acc3[j];
        vv[j] = ypc0*acc0[j] + ypc1*acc1[j] + ypc2*acc2[j] + ypc3*acc3[j];
    }
    #pragma unroll
    for (int m = 1; m < 32; m <<= 1) {
        #pragma unroll
        for (int j = 0; j < 8; ++j) {
            vv[j] += __shfl_xor(vv[j], m, 64);
            ww[j] += __shfl_xor(ww[j], m, 64);
        }
    }

    // ---- B fragments (pre-scaled by log2e) ----
    bf16x8 B0, B1, B2, B3;
    #pragma unroll
    for (int j = 0; j < 8; ++j) {
        B0[j] = (__bf16)(acc0[j] * LOG2E);
        B1[j] = (__bf16)(acc1[j] * LOG2E);
        B2[j] = (__bf16)(acc2[j] * LOG2E);
        B3[j] = (__bf16)(acc3[j] * LOG2E);
    }

    __syncthreads();                          // sync2: all LDS reads done
    // ---- write f32 u_ slice for patch rows (overwrites staging) ----
    {
        float* dst = u_slice + wid * N_BS * CB + r * CB + h * 8;
        *(float4*)(dst + 0*32*CB)     = make_float4(acc0[0],acc0[1],acc0[2],acc0[3]);
        *(float4*)(dst + 0*32*CB + 4) = make_float4(acc0[4],acc0[5],acc0[6],acc0[7]);
        *(float4*)(dst + 1*32*CB)     = make_float4(acc1[0],acc1[1],acc1[2],acc1[3]);
        *(float4*)(dst + 1*32*CB + 4) = make_float4(acc1[4],acc1[5],acc1[6],acc1[7]);
        *(float4*)(dst + 2*32*CB)     = make_float4(acc2[0],acc2[1],acc2[2],acc2[3]);
        *(float4*)(dst + 2*32*CB + 4) = make_float4(acc2[4],acc2[5],acc2[6],acc2[7]);
        *(float4*)(dst + 3*32*CB)     = make_float4(acc3[0],acc3[1],acc3[2],acc3[3]);
        *(float4*)(dst + 3*32*CB + 4) = make_float4(acc3[4],acc3[5],acc3[6],acc3[7]);
    }
    __syncthreads();                          // sync3: u_slice + pflag ready

    // ---- tile loop (identical to R12; zero barriers) ----
    float acc = 0.f;
    f32x16 zc = {};
    #pragma unroll 1
    for (int w = 0; w < nw; ++w) {
        const int t0  = (by + w * GY) * 32;
        const int row = t0 + r;
        const int rc  = (row < n_train) ? row : (n_train - 1);
        const float* __restrict__ ar = U + ((size_t)rc * n_cls + c) * CB + h * 8;
        float4 a0 = *(const float4*)(ar);
        float4 a1 = *(const float4*)(ar + 4);
        float Yv = Yb[(size_t)rc * n_cls + c];

        const int pf = pflag[w * 32 + r];
        if (pf >= 0) {
            const float* src = u_slice + wid * N_BS * CB + pf * CB + h * 8;
            a0 = *(const float4*)(src);
            a1 = *(const float4*)(src + 4);
            Yv = y[(size_t)pf * n_cls + c];
        }
        if (row >= n_train) {
            a0 = make_float4(0.f, 0.f, 0.f, 0.f); a1 = a0; Yv = 0.f;
        }

        // side dots vs in-register vvec/wvec halves
        float sv = a0.x*vv[0] + a0.y*vv[1] + a0.z*vv[2] + a0.w*vv[3]
                 + a1.x*vv[4] + a1.y*vv[5] + a1.z*vv[6] + a1.w*vv[7];
        float sw = a0.x*ww[0] + a0.y*ww[1] + a0.z*ww[2] + a0.w*ww[3]
                 + a1.x*ww[4] + a1.y*ww[5] + a1.z*ww[6] + a1.w*ww[7];

        bf16x8 A;
        A[0] = (__bf16)a0.x; A[1] = (__bf16)a0.y;
        A[2] = (__bf16)a0.z; A[3] = (__bf16)a0.w;
        A[4] = (__bf16)a1.x; A[5] = (__bf16)a1.y;
        A[6] = (__bf16)a1.z; A[7] = (__bf16)a1.w;

        float accA = 0.f;    // sum |ip'| this tile
        float pp   = 1.f;    // prod (1 + 2^-|ip'|), 64 factors in (1,2]
        #pragma unroll
        for (int bt = 0; bt < 4; ++bt) {
            bf16x8 Bf = (bt == 0) ? B0 : (bt == 1) ? B1 : (bt == 2) ? B2 : B3;
            f32x16 D = __builtin_amdgcn_mfma_f32_32x32x16_bf16(A, Bf, zc,
                                                               0, 0, 0);
            float a[16];
            #pragma unroll
            for (int j = 0; j < 16; ++j) {
                float ipa = fabsf(D[j]);
                a[j] = 1.0f + __builtin_amdgcn_exp2f(-ipa);
                accA += ipa;
            }
            #pragma unroll
            for (int s = 1; s < 16; s <<= 1)
                #pragma unroll
                for (int j = 0; j < 16; j += 2 * s) a[j] *= a[j + s];
            pp *= a[0];
        }
        float accL = __builtin_amdgcn_logf(pp);   // v_log_f32 = log2
        acc += LN2F * accL + (0.5f * LN2F) * accA + 0.5f * sw - Yv * sv;
    }

    // per-wave reduction only; no block reduce, no sync
    #pragma unroll
    for (int off = 32; off > 0; off >>= 1)
        acc += __shfl_down(acc, off, 64);
    if (lane == 0) {
        int bid = by * gridDim.x + bx;
        partials[bid * 4 + wid] = acc;
    }
}

__global__ __launch_bounds__(256) void finalize_kernel(
        const float* __restrict__ partials, int nblk,
        const float* __restrict__ quant_partials, int n_quant,
        float* __restrict__ out, double pad_corr,
        double like_scale, double quant_scale) {
    double s = 0.0, q = 0.0;
    for (int i = threadIdx.x; i < nblk; i += 256) s += (double)partials[i];
    for (int i = threadIdx.x; i < n_quant; i += 256) q += (double)quant_partials[i];
    #pragma unroll
    for (int off = 32; off > 0; off >>= 1) {
        s += __shfl_down(s, off, 64);
        q += __shfl_down(q, off, 64);
    }
    __shared__ double dred[4][2];
    int lane = threadIdx.x & 63, wid = threadIdx.x >> 6;
    if (lane == 0) { dred[wid][0] = s; dred[wid][1] = q; }
    __syncthreads();
    if (threadIdx.x == 0) {
        double S = dred[0][0] + dred[1][0] + dred[2][0] + dred[3][0];
        double Q = dred[0][1] + dred[1][1] + dred[2][1] + dred[3][1];
        out[0] = (float)((S - pad_corr) * like_scale + Q * quant_scale);
    }
}

extern "C" void kernel_launch(void* const* d_in, const int* in_sizes, int n_in,
                              void* d_out, int out_size, void* d_ws, size_t ws_size,
                              hipStream_t stream) {
    const float* u   = (const float*)d_in[0];
    const float* y   = (const float*)d_in[1];
    const int*   ind = (const int*)d_in[2];
    const float* U   = (const float*)d_in[3];
    const float* Yb  = (const float*)d_in[4];
    const float* w_D = (const float*)d_in[5];

    const int n_bs    = in_sizes[2];             // 128 (== N_BS)
    const int n_cls   = in_sizes[1] / n_bs;      // 100
    const int n_train = in_sizes[4] / n_cls;     // 10000

    const int totalU = n_bs * n_cls * CB;
    const int ntile  = (n_train + 31) / 32;      // 313
    const int GY     = (ntile + MAXW - 1) / MAXW; // 40
    const int gx     = (n_cls + 3) / 4;          // 25
    const int nblk   = GY * gx;                  // 1000 blocks
    const int npart  = nblk * 4;                 // per-wave partials
    const int nquant = gx * 4;                   // 100 (by==0 column only)

    char* ws = (char*)d_ws;
    size_t off = 0;
    float* partials = (float*)(ws + off);        off += (size_t)npart * 4;
    float* quant_partials = (float*)(ws + off);  off += (size_t)nquant * 4;

    loss_fused<<<dim3(gx, GY), 256, 0, stream>>>(
        u, y, w_D, U, Yb, ind, partials, quant_partials,
        n_cls, n_train, ntile, GY);

    const double ln2 = 0.6931471805599453;
    const double n_pad = (double)((long long)(ntile * 32 - n_train) *
                                  (long long)n_bs * (long long)n_cls);
    const double pad_corr    = ln2 * n_pad;
    const double like_scale  = 1.0 / ((double)n_bs * n_train * n_cls);
    const double quant_scale = (double)ALPHA / (double)totalU;

    finalize_kernel<<<1, 256, 0, stream>>>(partials, npart,
                                           quant_partials, nquant,
                                           (float*)d_out, pad_corr,
                                           like_scale, quant_scale);
}